// Round 8
// baseline (9131.162 us; speedup 1.0000x reference)
//
#include <hip/hip_runtime.h>

// Problem constants
#define B_   32
#define T_   256
#define N_   128
#define DIN_ 16
#define U_   64

// LDS (ushort): diffb [128 nodes][PD] node-major; difT [128 ch][PT] ch-major
#define PD 456   // cols: L1 uses 0..447; 456 ush = 228 dw (=4 mod 32 banks), 16B-aligned rows
#define PT 136
#define LDS_BYTES ((N_*PD + N_*PT)*2)   // 151552 B

// Workspace (ushort elems)
#define WT0G_OFF 0
#define WT0C_OFF (128*256)
#define WT1G_OFF (WT0C_OFF + 64*256)
#define WT1C_OFF (WT1G_OFF + 128*384)
#define WT_TOTAL (WT1C_OFF + 64*384)
#define S2_OFF   WT_TOTAL                 // bf16 S2[128][128]
#define FIFO_OFF (S2_OFF + 128*128)       // h0' stream: [b][t%8] x 8192 ush (16KB)
#define FIFO_SLOT(bb,tt) (FIFO_OFF + ((bb)*8 + ((tt)&7))*8192)
#define FLG_BYTE ((FIFO_OFF + 32*8*8192)*2)  // int prod[32]; int cons[32]

typedef __attribute__((ext_vector_type(8))) short bfrag;
typedef __attribute__((ext_vector_type(4))) float ffrag;
typedef __attribute__((ext_vector_type(4))) unsigned short us4;
typedef __attribute__((ext_vector_type(2))) unsigned short us2;
typedef unsigned long long ull;

// LDS-only barrier (no vmcnt drain -> weight/FIFO prefetches stay in flight)
#define SYNC() asm volatile("s_waitcnt lgkmcnt(0)\n\ts_barrier" ::: "memory")
#define MFMA16(a,b,c) __builtin_amdgcn_mfma_f32_16x16x32_bf16(a,b,c,0,0,0)

__device__ __forceinline__ unsigned short f2b(float x) {
  union { float f; unsigned u; } v; v.f = x;
  return (unsigned short)((v.u + 0x7fffu + ((v.u >> 16) & 1u)) >> 16);
}
__device__ __forceinline__ float sigm(float x) {
  float e = __expf(-x);
  return __builtin_amdgcn_rcpf(1.f + e);
}
__device__ __forceinline__ float tanh_(float x) {
  float e = __expf(2.f * x);
  return 1.f - 2.f * __builtin_amdgcn_rcpf(1.f + e);
}

// L0 gate k-map (K=256): [x dm0 16 | x dm12 32 | zero 16 | h dm0 64 | h dm12 128]
__device__ __forceinline__ float wval0(const float* w, int ncol, int co, int k) {
  if (k < 16)  return w[(k*3+0)*ncol+co] - w[(k*3+2)*ncol+co];
  if (k < 48)  { int j=k-16, c=j>>1;
                 return (j&1) ? 2.f*w[(c*3+2)*ncol+co] : w[(c*3+1)*ncol+co]; }
  if (k < 64)  return 0.f;
  if (k < 128) { int c=16+(k-64); return w[(c*3+0)*ncol+co] - w[(c*3+2)*ncol+co]; }
  { int j=k-128, c=16+(j>>1);
    return (j&1) ? 2.f*w[(c*3+2)*ncol+co] : w[(c*3+1)*ncol+co]; }
}
// L1 gate k-map (K=384): [h0' dm0 64 | h0' dm12 128 | h1 dm0 64 | h1 dm12 128]
__device__ __forceinline__ float wval1(const float* w, int ncol, int co, int k) {
  if (k < 64)  return w[(k*3+0)*ncol+co] - w[(k*3+2)*ncol+co];
  if (k < 192) { int j=k-64, c=j>>1;
                 return (j&1) ? 2.f*w[(c*3+2)*ncol+co] : w[(c*3+1)*ncol+co]; }
  if (k < 256) { int c=64+(k-192); return w[(c*3+0)*ncol+co] - w[(c*3+2)*ncol+co]; }
  { int j=k-256, c=64+(j>>1);
    return (j&1) ? 2.f*w[(c*3+2)*ncol+co] : w[(c*3+1)*ncol+co]; }
}
// cand k-orders (rh double-buffered): L0 [x 64 | rh dm12 128 | rh dm0 64]
__device__ __forceinline__ float wval0c(const float* w, int ncol, int co, int k) {
  if (k < 64)  return wval0(w, ncol, co, k);
  if (k < 192) return wval0(w, ncol, co, k + 64);   // rh dm12 -> h dm12 weights
  return wval0(w, ncol, co, k - 128);               // rh dm0  -> h dm0 weights
}
// L1 [h0' 192 | rh dm12 128 | rh dm0 64]
__device__ __forceinline__ float wval1c(const float* w, int ncol, int co, int k) {
  if (k < 192) return wval1(w, ncol, co, k);
  if (k < 320) return wval1(w, ncol, co, k + 64);   // rh dm12 -> h1 dm12 weights
  return wval1(w, ncol, co, k - 128);               // rh dm0  -> h1 dm0 weights
}

__global__ void setup_wt(const float* __restrict__ w0g, const float* __restrict__ w0c,
                         const float* __restrict__ w1g, const float* __restrict__ w1c,
                         unsigned short* __restrict__ wt) {
  int i = blockIdx.x * blockDim.x + threadIdx.x;
  if (i >= WT_TOTAL) return;
  float v;
  if (i < WT0C_OFF)      { int co = i >> 8, k = i & 255;                 v = wval0 (w0g, 128, co, k); }
  else if (i < WT1G_OFF) { int j = i - WT0C_OFF; v = wval0c(w0c, 64, j >> 8, j & 255); }
  else if (i < WT1C_OFF) { int j = i - WT1G_OFF; v = wval1 (w1g, 128, j / 384, j % 384); }
  else                   { int j = i - WT1C_OFF; v = wval1c(w1c, 64, j / 384, j % 384); }
  wt[i] = f2b(v);
}

__global__ void setup_s2(const float* __restrict__ sup, unsigned short* __restrict__ s2) {
  int idx = blockIdx.x * blockDim.x + threadIdx.x;
  int i = idx >> 7, j = idx & 127;
  float acc = 0.f;
#pragma unroll 4
  for (int k = 0; k < 128; ++k) acc += sup[i*128 + k] * sup[k*128 + j];
  s2[idx] = f2b(acc);
}

__global__ void zero_flags(unsigned short* __restrict__ wt) {
  int* flg = (int*)((char*)wt + FLG_BYTE);
  if (threadIdx.x < 64) flg[threadIdx.x] = 0;
}

// GEMM pass: own 16-row strip x 4 co-tiles, contiguous K, ring 4-deep.
template<int KT>
__device__ __forceinline__ void gpass(ffrag (&acc)[4], bfrag (&bw)[16],
    const unsigned short* __restrict__ arow,
    const unsigned short* const (&bp)[4], const int lq) {
#pragma unroll
  for (int ks = 0; ks < KT; ++ks) {
    const int k = ks & 3;
    bfrag a = *(const bfrag*)&arow[32*ks + 8*lq];
    bfrag b0 = bw[4*k], b1 = bw[4*k+1], b2 = bw[4*k+2], b3 = bw[4*k+3];
    if (ks + 4 < KT) {
#pragma unroll
      for (int n = 0; n < 4; ++n)
        bw[4*k+n] = *(const bfrag*)&bp[n][32*(ks+4) + 8*lq];
    }
    acc[0] = MFMA16(a, b0, acc[0]);
    acc[1] = MFMA16(a, b1, acc[1]);
    acc[2] = MFMA16(a, b2, acc[2]);
    acc[3] = MFMA16(a, b3, acc[3]);
  }
}
// cand pass: same but A columns from a ks-offset list (weights contiguous).
template<int KT>
__device__ __forceinline__ void cpass(ffrag (&acc)[4], bfrag (&bw)[16],
    const unsigned short* __restrict__ arow, const int (&kofs)[KT],
    const unsigned short* const (&bp)[4], const int lq) {
#pragma unroll
  for (int ks = 0; ks < KT; ++ks) {
    const int k = ks & 3;
    bfrag a = *(const bfrag*)&arow[kofs[ks] + 8*lq];
    bfrag b0 = bw[4*k], b1 = bw[4*k+1], b2 = bw[4*k+2], b3 = bw[4*k+3];
    if (ks + 4 < KT) {
#pragma unroll
      for (int n = 0; n < 4; ++n)
        bw[4*k+n] = *(const bfrag*)&bp[n][32*(ks+4) + 8*lq];
    }
    acc[0] = MFMA16(a, b0, acc[0]);
    acc[1] = MFMA16(a, b1, acc[1]);
    acc[2] = MFMA16(a, b2, acc[2]);
    acc[3] = MFMA16(a, b3, acc[3]);
  }
}

__global__ __launch_bounds__(512, 2) void dcgru(
    const float* __restrict__ xseq, const int* __restrict__ slen,
    const float* __restrict__ sup,
    const float* __restrict__ b0g, const float* __restrict__ b0c,
    const float* __restrict__ b1g, const float* __restrict__ b1c,
    const float* __restrict__ wfc, const float* __restrict__ bfc,
    unsigned short* __restrict__ wt, float* __restrict__ out) {
  extern __shared__ unsigned short lds[];
  unsigned short* diffb = lds;
  unsigned short* difT  = lds + N_*PD;
  const int b    = blockIdx.x >> 1;
  const int eta  = blockIdx.x & 1;        // 0 = layer-0 producer, 1 = layer-1 consumer
  const int tid  = threadIdx.x;
  const int w    = tid >> 6;              // wave 0..7: owns rows [16w, 16w+16)
  const int ln   = tid & 15;
  const int lq   = (tid >> 4) & 3;
  const int L    = slen[b];
  int* flg  = (int*)((char*)wt + FLG_BYTE);
  int* prod = flg + b;
  int* cons = flg + 32 + b;
  const unsigned short* __restrict__ arow = diffb + (16*w + ln)*PD;
  const ffrag fz = {0.f, 0.f, 0.f, 0.f};

  // S / S2 A-frags for own strip only (8 bfrags = 32 VGPR)
  bfrag Sf[4], S2f[4];
#pragma unroll
  for (int ks = 0; ks < 4; ++ks) {
    const float* pS = sup + (16*w + ln)*N_ + 32*ks + 8*lq;
    union { bfrag v; unsigned short u[8]; } tmp;
#pragma unroll
    for (int j = 0; j < 8; ++j) tmp.u[j] = f2b(pS[j]);
    Sf[ks] = tmp.v;
    S2f[ks] = *(const bfrag*)&wt[S2_OFF + (16*w + ln)*N_ + 32*ks + 8*lq];
  }

  // diffuse ch-tile nt: dm1=S@xc, dm2=S2@xc for OWN rows; interleaved cols colc+2ln+{0,1}
  auto diffuse = [&](int nt, int colc) {
    bfrag bf[4];
#pragma unroll
    for (int ks = 0; ks < 4; ++ks)
      bf[ks] = *(const bfrag*)&difT[(16*nt + ln)*PT + 32*ks + 8*lq];
    ffrag a1 = fz, a2 = fz;
#pragma unroll
    for (int ks = 0; ks < 4; ++ks) {
      a1 = MFMA16(Sf[ks],  bf[ks], a1);
      a2 = MFMA16(S2f[ks], bf[ks], a2);
    }
    const int n0 = 16*w + 4*lq;
    const int col = colc + 2*ln;
#pragma unroll
    for (int r = 0; r < 4; ++r) {
      us2 pq = {f2b(a1[r]), f2b(a2[r])};
      *(us2*)&diffb[(n0 + r)*PD + col] = pq;
    }
  };
  // dump own-strip 4-co C-frags: node-major / ch-major separately
  auto dumpD = [&](ffrag (&v)[4], int colBase) {
    const int n0 = 16*w + 4*lq;
#pragma unroll
    for (int co = 0; co < 4; ++co) {
      const int ch = 16*co + ln;
#pragma unroll
      for (int r = 0; r < 4; ++r) diffb[(n0 + r)*PD + colBase + ch] = f2b(v[co][r]);
    }
  };
  auto dumpT = [&](ffrag (&v)[4], int rowBase) {
    const int n0 = 16*w + 4*lq;
#pragma unroll
    for (int co = 0; co < 4; ++co) {
      const int ch = 16*co + ln;
      us4 q = {f2b(v[co][0]), f2b(v[co][1]), f2b(v[co][2]), f2b(v[co][3])};
      *(us4*)&difT[(rowBase + ch)*PT + n0] = q;
    }
  };
  auto preb4 = [&](bfrag (&bw)[16], const unsigned short* const (&bp)[4]) {
#pragma unroll
    for (int k = 0; k < 4; ++k)
#pragma unroll
      for (int n = 0; n < 4; ++n)
        bw[4*k+n] = *(const bfrag*)&bp[n][32*k + 8*lq];
  };
  auto waitge = [&](int* p, int seq) {
    if ((tid & 63) == 0) {
      int it = 0;
      while (__hip_atomic_load(p, __ATOMIC_RELAXED, __HIP_MEMORY_SCOPE_AGENT) < seq) {
        __builtin_amdgcn_s_sleep(4);
        if (++it > (1 << 22)) break;            // failsafe: never hard-hang
      }
    }
  };

  bfrag bwR[16], bwU[16], bwC[16];

  if (eta == 0) {
    // ========== Block A: layer-0. cols [x16|xdm12 32|z16|h dm0 64|h dm12 128|rh dm0 64] ==========
    const unsigned short* bpgr[4] = {
      wt + WT0G_OFF + (ln)*256,            wt + WT0G_OFF + (16 + ln)*256,
      wt + WT0G_OFF + (32 + ln)*256,       wt + WT0G_OFF + (48 + ln)*256 };
    const unsigned short* bpgu[4] = {
      wt + WT0G_OFF + (64 + ln)*256,       wt + WT0G_OFF + (80 + ln)*256,
      wt + WT0G_OFF + (96 + ln)*256,       wt + WT0G_OFF + (112 + ln)*256 };
    const unsigned short* bpc[4] = {
      wt + WT0C_OFF + (ln)*256,            wt + WT0C_OFF + (16 + ln)*256,
      wt + WT0C_OFF + (32 + ln)*256,       wt + WT0C_OFF + (48 + ln)*256 };
    const float bgr[4] = { b0g[ln], b0g[16+ln], b0g[32+ln], b0g[48+ln] };
    const float bgu[4] = { b0g[64+ln], b0g[80+ln], b0g[96+ln], b0g[112+ln] };
    const float bcv[4] = { b0c[ln], b0c[16+ln], b0c[32+ln], b0c[48+ln] };
    const int kofs0[8] = {0, 32, 128, 160, 192, 224, 256, 288};
    ffrag h0m[4] = {fz, fz, fz, fz};

    for (int i = tid; i < N_*16; i += 512)     // zero pad cols [48,64) once
      diffb[(i >> 4)*PD + 48 + (i & 15)] = 0;
    float4 xv = *(const float4*)&xseq[(size_t)(b*T_)*N_*DIN_ + 4*tid];

#pragma clang loop unroll(disable)
    for (int t = 0; t < L; ++t) {
      { // P1: stage x (cols 0-15 / difT rows 0-15); dump h0 (cols 64-127 / rows 16-79)
        const int node = tid >> 2, c = 4*(tid & 3);
        unsigned short s0 = f2b(xv.x), s1 = f2b(xv.y), s2 = f2b(xv.z), s3 = f2b(xv.w);
        us4 q = {s0, s1, s2, s3};
        *(us4*)&diffb[node*PD + c] = q;
        difT[(c+0)*PT + node] = s0; difT[(c+1)*PT + node] = s1;
        difT[(c+2)*PT + node] = s2; difT[(c+3)*PT + node] = s3;
        dumpD(h0m, 64); dumpT(h0m, 16);
        int tn = t + 1 < L ? t + 1 : L - 1;
        xv = *(const float4*)&xseq[(size_t)(b*T_ + tn)*N_*DIN_ + 4*tid];
        preb4(bwR, bpgr);
      }
      SYNC();                                            // BAR1
      // phase A: diffuse-1 (all own rows) -> gate -> activations -> rh diffb dump
      diffuse(0, 16);
      diffuse(1, 128); diffuse(2, 160); diffuse(3, 192); diffuse(4, 224);
      ffrag gaR[4] = {fz, fz, fz, fz};
      gpass<8>(gaR, bwR, arow, bpgr, lq);
      preb4(bwU, bpgu);
      ffrag rh[4], u0s[4];
#pragma unroll
      for (int co = 0; co < 4; ++co)
#pragma unroll
        for (int r = 0; r < 4; ++r)
          rh[co][r] = sigm(gaR[co][r] + bgr[co]) * h0m[co][r];
      ffrag gaU[4] = {fz, fz, fz, fz};
      gpass<8>(gaU, bwU, arow, bpgu, lq);
#pragma unroll
      for (int co = 0; co < 4; ++co)
#pragma unroll
        for (int r = 0; r < 4; ++r)
          u0s[co][r] = sigm(gaU[co][r] + bgu[co]);
      dumpD(rh, 256);                                    // rh dm0 -> cols 256-319
      SYNC();                                            // BAR2 (difT h0-row reads done)
      dumpT(rh, 16);                                     // rh -> difT rows 16-79
      preb4(bwC, bpc);
      SYNC();                                            // BAR3
      // phase B: diffuse-2 -> cand -> update
      diffuse(1, 128); diffuse(2, 160); diffuse(3, 192); diffuse(4, 224);
      ffrag ca[4] = {fz, fz, fz, fz};
      cpass<8>(ca, bwC, arow, kofs0, bpc, lq);
#pragma unroll
      for (int co = 0; co < 4; ++co)
#pragma unroll
        for (int r = 0; r < 4; ++r) {
          float cc = tanh_(ca[co][r] + bcv[co]);
          float uu = u0s[co][r];
          h0m[co][r] = uu*h0m[co][r] + (1.f - uu)*cc;
        }
      if (t >= 8) waitge(cons, t - 7);                   // FIFO backpressure
      { // send h0' ch-major [64 ch][128 nodes]
        unsigned short* slot = wt + FIFO_SLOT(b, t);
        const int n0 = 16*w + 4*lq;
#pragma unroll
        for (int co = 0; co < 4; ++co) {
          const int ch = 16*co + ln;
          us4 q = {f2b(h0m[co][0]), f2b(h0m[co][1]), f2b(h0m[co][2]), f2b(h0m[co][3])};
          *(us4*)&slot[ch*128 + n0] = q;
        }
      }
      __syncthreads();                                   // BAR4: drain sends
      if (tid == 0)
        __hip_atomic_fetch_add(prod, 1, __ATOMIC_RELEASE, __HIP_MEMORY_SCOPE_AGENT);
    }
    return;
  }

  // ========== Block B: layer-1. cols [h0' dm0 64|h0' dm12 128|h1 dm0 64|h1/rh dm12 128|rh dm0 64] ==========
  {
    const unsigned short* bpgr[4] = {
      wt + WT1G_OFF + (ln)*384,            wt + WT1G_OFF + (16 + ln)*384,
      wt + WT1G_OFF + (32 + ln)*384,       wt + WT1G_OFF + (48 + ln)*384 };
    const unsigned short* bpgu[4] = {
      wt + WT1G_OFF + (64 + ln)*384,       wt + WT1G_OFF + (80 + ln)*384,
      wt + WT1G_OFF + (96 + ln)*384,       wt + WT1G_OFF + (112 + ln)*384 };
    const unsigned short* bpc[4] = {
      wt + WT1C_OFF + (ln)*384,            wt + WT1C_OFF + (16 + ln)*384,
      wt + WT1C_OFF + (32 + ln)*384,       wt + WT1C_OFF + (48 + ln)*384 };
    const float bgr[4] = { b1g[ln], b1g[16+ln], b1g[32+ln], b1g[48+ln] };
    const float bgu[4] = { b1g[64+ln], b1g[80+ln], b1g[96+ln], b1g[112+ln] };
    const float bcv[4] = { b1c[ln], b1c[16+ln], b1c[32+ln], b1c[48+ln] };
    const int kofs1[12] = {0, 32, 64, 96, 128, 160, 256, 288, 320, 352, 384, 416};
    ffrag h1m[4] = {fz, fz, fz, fz};
    ull pf[4];

    auto loadPf = [&](int tt) {
      const unsigned short* slot = wt + FIFO_SLOT(b, tt);
#pragma unroll
      for (int rep = 0; rep < 4; ++rep) {
        const int idx = tid + 512*rep;
        const int ch = idx >> 5, n0 = (idx & 31)*4;
        pf[rep] = __hip_atomic_load((const ull*)&slot[ch*128 + n0],
                                    __ATOMIC_RELAXED, __HIP_MEMORY_SCOPE_AGENT);
      }
    };

    waitge(prod, 1);
    loadPf(0);

#pragma clang loop unroll(disable)
    for (int t = 0; t < L; ++t) {
      { // P1: scatter h0'(t) from regs; dump h1 (cols 192-255 / difT rows 64-127)
#pragma unroll
        for (int rep = 0; rep < 4; ++rep) {
          const int idx = tid + 512*rep;
          const int ch = idx >> 5, n0 = (idx & 31)*4;
          *(ull*)&difT[ch*PT + n0] = pf[rep];
          union { ull u; unsigned short s[4]; } cv; cv.u = pf[rep];
#pragma unroll
          for (int j = 0; j < 4; ++j) diffb[(n0 + j)*PD + ch] = cv.s[j];
        }
        dumpD(h1m, 192); dumpT(h1m, 64);
        preb4(bwR, bpgr);
      }
      SYNC();                                            // BAR1
      if (tid == 0)
        __hip_atomic_fetch_add(cons, 1, __ATOMIC_RELEASE, __HIP_MEMORY_SCOPE_AGENT);
      { // prefetch next FIFO slot into regs (off critical path; A is ~1+ steps ahead)
        int sq = t + 2 < L ? t + 2 : L;
        waitge(prod, sq);
        loadPf(t + 1 < L ? t + 1 : L - 1);
      }
      // phase A: diffuse-1 (8 tiles, own rows) -> gate -> activations -> rh dm0 dump
      diffuse(0, 64);  diffuse(1, 96);  diffuse(2, 128); diffuse(3, 160);
      diffuse(4, 256); diffuse(5, 288); diffuse(6, 320); diffuse(7, 352);
      ffrag gaR[4] = {fz, fz, fz, fz};
      gpass<12>(gaR, bwR, arow, bpgr, lq);
      preb4(bwU, bpgu);
      ffrag rh[4], u1s[4];
#pragma unroll
      for (int co = 0; co < 4; ++co)
#pragma unroll
        for (int r = 0; r < 4; ++r)
          rh[co][r] = sigm(gaR[co][r] + bgr[co]) * h1m[co][r];
      ffrag gaU[4] = {fz, fz, fz, fz};
      gpass<12>(gaU, bwU, arow, bpgu, lq);
#pragma unroll
      for (int co = 0; co < 4; ++co)
#pragma unroll
        for (int r = 0; r < 4; ++r)
          u1s[co][r] = sigm(gaU[co][r] + bgu[co]);
      dumpD(rh, 384);                                    // rh dm0 -> cols 384-447
      SYNC();                                            // BAR2 (difT h1-row reads done)
      dumpT(rh, 64);                                     // rh -> difT rows 64-127
      preb4(bwC, bpc);
      SYNC();                                            // BAR3
      // phase B: diffuse-2 (rh tiles) -> cand -> update
      diffuse(4, 256); diffuse(5, 288); diffuse(6, 320); diffuse(7, 352);
      ffrag ca[4] = {fz, fz, fz, fz};
      cpass<12>(ca, bwC, arow, kofs1, bpc, lq);
#pragma unroll
      for (int co = 0; co < 4; ++co)
#pragma unroll
        for (int r = 0; r < 4; ++r) {
          float cc = tanh_(ca[co][r] + bcv[co]);
          float uu = u1s[co][r];
          h1m[co][r] = uu*h1m[co][r] + (1.f - uu)*cc;
        }
      SYNC();                                            // BAR4 (cand reads done)
    }

    // Head: relu(h1) @ W_fc + b_fc, max over nodes
    {
      float* hb = (float*)lds;                  // [128][64]
      const int n0 = 16*w + 4*lq;
#pragma unroll
      for (int co = 0; co < 4; ++co)
#pragma unroll
        for (int r = 0; r < 4; ++r) {
          float v = h1m[co][r];
          hb[(n0 + r)*U_ + 16*co + ln] = v > 0.f ? v : 0.f;
        }
    }
    __syncthreads();
    float* hb = (float*)lds;
    float* lb = hb + N_*U_;
    if (tid < N_) {
      float lg[4];
#pragma unroll
      for (int j = 0; j < 4; ++j) lg[j] = bfc[j];
      for (int ch = 0; ch < U_; ++ch) {
        float v = hb[tid*U_ + ch];
#pragma unroll
        for (int j = 0; j < 4; ++j) lg[j] += v * wfc[ch*4 + j];
      }
#pragma unroll
      for (int j = 0; j < 4; ++j) lb[tid*4 + j] = lg[j];
    }
    __syncthreads();
    if (tid < 4) {
      float m = lb[tid];
      for (int n = 1; n < N_; ++n) m = fmaxf(m, lb[n*4 + tid]);
      out[b*4 + tid] = m;
    }
  }
}

extern "C" void kernel_launch(void* const* d_in, const int* in_sizes, int n_in,
                              void* d_out, int out_size, void* d_ws, size_t ws_size,
                              hipStream_t stream) {
  const float* xseq = (const float*)d_in[0];
  const int*   slen = (const int*)  d_in[1];
  const float* sup  = (const float*)d_in[2];
  const float* w0g  = (const float*)d_in[3];
  const float* b0g  = (const float*)d_in[4];
  const float* w0c  = (const float*)d_in[5];
  const float* b0c  = (const float*)d_in[6];
  const float* w1g  = (const float*)d_in[7];
  const float* b1g  = (const float*)d_in[8];
  const float* w1c  = (const float*)d_in[9];
  const float* b1c  = (const float*)d_in[10];
  const float* wfc  = (const float*)d_in[11];
  const float* bfc  = (const float*)d_in[12];
  float* out = (float*)d_out;
  unsigned short* wt = (unsigned short*)d_ws;

  (void)hipFuncSetAttribute((const void*)dcgru,
                            hipFuncAttributeMaxDynamicSharedMemorySize, LDS_BYTES);
  zero_flags<<<dim3(1), dim3(64), 0, stream>>>(wt);
  setup_wt<<<dim3((WT_TOTAL + 255)/256), dim3(256), 0, stream>>>(w0g, w0c, w1g, w1c, wt);
  setup_s2<<<dim3(64), dim3(256), 0, stream>>>(sup, wt + S2_OFF);
  dcgru<<<dim3(64), dim3(512), LDS_BYTES, stream>>>(
      xseq, slen, sup, b0g, b0c, b1g, b1c, wfc, bfc, wt, out);
}

// Round 9
// 5300.255 us; speedup vs baseline: 1.7228x; 1.7228x over previous
//
#include <hip/hip_runtime.h>

// Problem constants
#define B_   32
#define T_   256
#define N_   128
#define DIN_ 16
#define U_   64

// LDS (ushort): diffb [128 nodes][PD] node-major; difT [128 ch][PT] ch-major
#define PD 456   // B uses cols 0..447; 912B row stride = 57*16 (b128-aligned rows)
#define PT 136
#define LDS_BYTES ((N_*PD + N_*PT)*2)   // 151552 B

// Workspace (ushort elems)
#define WT0G_OFF 0
#define WT0C_OFF (128*256)
#define WT1G_OFF (WT0C_OFF + 64*256)
#define WT1C_OFF (WT1G_OFF + 128*384)
#define WT_TOTAL (WT1C_OFF + 64*384)
#define S2_OFF   WT_TOTAL                 // bf16 S2[128][128]
#define FIFO_OFF (S2_OFF + 128*128)       // h0' stream: [b][t%8] x 8192 ush (16KB)
#define FIFO_SLOT(bb,tt) (FIFO_OFF + ((bb)*8 + ((tt)&7))*8192)
#define FLG_BYTE ((FIFO_OFF + 32*8*8192)*2)  // int prod[32]; int cons[32]

typedef __attribute__((ext_vector_type(8))) short bfrag;
typedef __attribute__((ext_vector_type(4))) float ffrag;
typedef __attribute__((ext_vector_type(4))) unsigned short us4;
typedef __attribute__((ext_vector_type(2))) unsigned short us2;
typedef unsigned long long ull;

// LDS-only barrier (no vmcnt drain -> weight/FIFO prefetches stay in flight)
#define SYNC() asm volatile("s_waitcnt lgkmcnt(0)\n\ts_barrier" ::: "memory")
#define MFMA16(a,b,c) __builtin_amdgcn_mfma_f32_16x16x32_bf16(a,b,c,0,0,0)

__device__ __forceinline__ unsigned short f2b(float x) {
  union { float f; unsigned u; } v; v.f = x;
  return (unsigned short)((v.u + 0x7fffu + ((v.u >> 16) & 1u)) >> 16);
}
__device__ __forceinline__ float sigm(float x) {
  float e = __expf(-x);
  return __builtin_amdgcn_rcpf(1.f + e);
}
__device__ __forceinline__ float tanh_(float x) {
  float e = __expf(2.f * x);
  return 1.f - 2.f * __builtin_amdgcn_rcpf(1.f + e);
}

// L0 gate k-map (K=256): [x dm0 16 | x dm12 32 | zero 16 | h dm0 64 | h dm12 128]
__device__ __forceinline__ float wval0(const float* w, int ncol, int co, int k) {
  if (k < 16)  return w[(k*3+0)*ncol+co] - w[(k*3+2)*ncol+co];
  if (k < 48)  { int j=k-16, c=j>>1;
                 return (j&1) ? 2.f*w[(c*3+2)*ncol+co] : w[(c*3+1)*ncol+co]; }
  if (k < 64)  return 0.f;
  if (k < 128) { int c=16+(k-64); return w[(c*3+0)*ncol+co] - w[(c*3+2)*ncol+co]; }
  { int j=k-128, c=16+(j>>1);
    return (j&1) ? 2.f*w[(c*3+2)*ncol+co] : w[(c*3+1)*ncol+co]; }
}
// L1 gate k-map (K=384): [h0' dm0 64 | h0' dm12 128 | h1 dm0 64 | h1 dm12 128]
__device__ __forceinline__ float wval1(const float* w, int ncol, int co, int k) {
  if (k < 64)  return w[(k*3+0)*ncol+co] - w[(k*3+2)*ncol+co];
  if (k < 192) { int j=k-64, c=j>>1;
                 return (j&1) ? 2.f*w[(c*3+2)*ncol+co] : w[(c*3+1)*ncol+co]; }
  if (k < 256) { int c=64+(k-192); return w[(c*3+0)*ncol+co] - w[(c*3+2)*ncol+co]; }
  { int j=k-256, c=64+(j>>1);
    return (j&1) ? 2.f*w[(c*3+2)*ncol+co] : w[(c*3+1)*ncol+co]; }
}
// cand k-orders (rh double-buffered):
// L0 cand cols: [x/zero 0-63 | rh dm12 @128-255 | rh dm0 @256-319]
__device__ __forceinline__ float wval0c(const float* w, int ncol, int co, int k) {
  if (k < 64)  return wval0(w, ncol, co, k);
  if (k < 192) return wval0(w, ncol, co, k + 64);   // rh dm12 -> h dm12 weights
  return wval0(w, ncol, co, k - 128);               // rh dm0  -> h dm0 weights
}
// L1 cand cols: [h0' 0-191 | rh dm12 @256-383 | rh dm0 @384-447]
__device__ __forceinline__ float wval1c(const float* w, int ncol, int co, int k) {
  if (k < 192) return wval1(w, ncol, co, k);
  if (k < 320) return wval1(w, ncol, co, k + 64);   // rh dm12 -> h1 dm12 weights
  return wval1(w, ncol, co, k - 128);               // rh dm0  -> h1 dm0 weights
}

__global__ void setup_wt(const float* __restrict__ w0g, const float* __restrict__ w0c,
                         const float* __restrict__ w1g, const float* __restrict__ w1c,
                         unsigned short* __restrict__ wt) {
  int i = blockIdx.x * blockDim.x + threadIdx.x;
  if (i >= WT_TOTAL) return;
  float v;
  if (i < WT0C_OFF)      { int co = i >> 8, k = i & 255;                 v = wval0 (w0g, 128, co, k); }
  else if (i < WT1G_OFF) { int j = i - WT0C_OFF; v = wval0c(w0c, 64, j >> 8, j & 255); }
  else if (i < WT1C_OFF) { int j = i - WT1G_OFF; v = wval1 (w1g, 128, j / 384, j % 384); }
  else                   { int j = i - WT1C_OFF; v = wval1c(w1c, 64, j / 384, j % 384); }
  wt[i] = f2b(v);
}

__global__ void setup_s2(const float* __restrict__ sup, unsigned short* __restrict__ s2) {
  int idx = blockIdx.x * blockDim.x + threadIdx.x;
  int i = idx >> 7, j = idx & 127;
  float acc = 0.f;
#pragma unroll 4
  for (int k = 0; k < 128; ++k) acc += sup[i*128 + k] * sup[k*128 + j];
  s2[idx] = f2b(acc);
}

__global__ void zero_flags(unsigned short* __restrict__ wt) {
  int* flg = (int*)((char*)wt + FLG_BYTE);
  if (threadIdx.x < 64) flg[threadIdx.x] = 0;
}

// Gate GEMM: 2 m-tiles x 4 co-tiles; contiguous K; 4-deep rolling ring (16 bfrags).
template<int KT>
__device__ __forceinline__ void gate4(ffrag (&acc)[2][4], bfrag (&bw)[16],
    const unsigned short* __restrict__ arow0, const unsigned short* __restrict__ arow1,
    const unsigned short* const (&bp)[4], const int lq) {
#pragma unroll
  for (int ks = 0; ks < KT; ++ks) {
    const int k = ks & 3;
    bfrag a0 = *(const bfrag*)&arow0[32*ks + 8*lq];
    bfrag a1 = *(const bfrag*)&arow1[32*ks + 8*lq];
    bfrag bb0 = bw[4*k], bb1 = bw[4*k+1], bb2 = bw[4*k+2], bb3 = bw[4*k+3];
    if (ks + 4 < KT) {
#pragma unroll
      for (int n = 0; n < 4; ++n)
        bw[4*k+n] = *(const bfrag*)&bp[n][32*(ks+4) + 8*lq];
    }
    acc[0][0] = MFMA16(a0, bb0, acc[0][0]);
    acc[1][0] = MFMA16(a1, bb0, acc[1][0]);
    acc[0][1] = MFMA16(a0, bb1, acc[0][1]);
    acc[1][1] = MFMA16(a1, bb1, acc[1][1]);
    acc[0][2] = MFMA16(a0, bb2, acc[0][2]);
    acc[1][2] = MFMA16(a1, bb2, acc[1][2]);
    acc[0][3] = MFMA16(a0, bb3, acc[0][3]);
    acc[1][3] = MFMA16(a1, bb3, acc[1][3]);
  }
}
// Cand GEMM: 2 m-tiles x 2 co-tiles; A-cols via ks-offset list (weights contiguous).
template<int KT>
__device__ __forceinline__ void cand2(ffrag (&acc)[2][2], bfrag (&bw)[8],
    const unsigned short* __restrict__ arow0, const unsigned short* __restrict__ arow1,
    const int (&kofs)[KT], const unsigned short* const (&bp)[2], const int lq) {
#pragma unroll
  for (int ks = 0; ks < KT; ++ks) {
    const int k = ks & 3;
    bfrag a0 = *(const bfrag*)&arow0[kofs[ks] + 8*lq];
    bfrag a1 = *(const bfrag*)&arow1[kofs[ks] + 8*lq];
    bfrag bb0 = bw[2*k], bb1 = bw[2*k+1];
    if (ks + 4 < KT) {
      bw[2*k]   = *(const bfrag*)&bp[0][32*(ks+4) + 8*lq];
      bw[2*k+1] = *(const bfrag*)&bp[1][32*(ks+4) + 8*lq];
    }
    acc[0][0] = MFMA16(a0, bb0, acc[0][0]);
    acc[1][0] = MFMA16(a1, bb0, acc[1][0]);
    acc[0][1] = MFMA16(a0, bb1, acc[0][1]);
    acc[1][1] = MFMA16(a1, bb1, acc[1][1]);
  }
}

__global__ __launch_bounds__(512, 2) void dcgru(
    const float* __restrict__ xseq, const int* __restrict__ slen,
    const float* __restrict__ sup,
    const float* __restrict__ b0g, const float* __restrict__ b0c,
    const float* __restrict__ b1g, const float* __restrict__ b1c,
    const float* __restrict__ wfc, const float* __restrict__ bfc,
    unsigned short* __restrict__ wt, float* __restrict__ out) {
  extern __shared__ unsigned short lds[];
  unsigned short* diffb = lds;
  unsigned short* difT  = lds + N_*PD;
  const int b    = blockIdx.x >> 1;
  const int eta  = blockIdx.x & 1;        // 0 = layer-0 producer, 1 = layer-1 consumer
  const int tid  = threadIdx.x;
  const int w    = tid >> 6;              // wave 0..7
  const int g    = w >> 1;                // node quad: nodes [32g, 32g+32)
  const int e    = w & 1;                 // tile-list half / ch half
  const int ln   = tid & 15;
  const int lq   = (tid >> 4) & 3;
  const int L    = slen[b];
  int* flg  = (int*)((char*)wt + FLG_BYTE);
  int* prod = flg + b;
  int* cons = flg + 32 + b;
  const unsigned short* __restrict__ arow0 = diffb + (32*g      + ln)*PD;
  const unsigned short* __restrict__ arow1 = diffb + (32*g + 16 + ln)*PD;
  const ffrag fz = {0.f, 0.f, 0.f, 0.f};

  // S / S2 A-frags for BOTH strips of this wave's node quad (16 bfrags);
  // one difT read feeds 2 strips' MFMAs.
  bfrag Sf[2][4], S2f[2][4];
#pragma unroll
  for (int si = 0; si < 2; ++si)
#pragma unroll
    for (int ks = 0; ks < 4; ++ks) {
      const float* pS = sup + (32*g + 16*si + ln)*N_ + 32*ks + 8*lq;
      union { bfrag v; unsigned short u[8]; } tmp;
#pragma unroll
      for (int j = 0; j < 8; ++j) tmp.u[j] = f2b(pS[j]);
      Sf[si][ks] = tmp.v;
      S2f[si][ks] = *(const bfrag*)&wt[S2_OFF + (32*g + 16*si + ln)*N_ + 32*ks + 8*lq];
    }

  // dm1=S@xc, dm2=S2@xc for ch-tile t (2 strips); interleaved cols colc + 2*ln + {0,1}
  auto diffuse = [&](int t, int colc) {
    bfrag bf[4];
#pragma unroll
    for (int ks = 0; ks < 4; ++ks)
      bf[ks] = *(const bfrag*)&difT[(16*t + ln)*PT + 32*ks + 8*lq];
#pragma unroll
    for (int si = 0; si < 2; ++si) {
      ffrag a1 = fz, a2 = fz;
#pragma unroll
      for (int ks = 0; ks < 4; ++ks) {
        a1 = MFMA16(Sf[si][ks],  bf[ks], a1);
        a2 = MFMA16(S2f[si][ks], bf[ks], a2);
      }
      const int n0 = 32*g + 16*si + 4*lq;
      const int col = colc + 2*ln;
#pragma unroll
      for (int r = 0; r < 4; ++r) {
        us2 pq = {f2b(a1[r]), f2b(a2[r])};
        *(us2*)&diffb[(n0 + r)*PD + col] = pq;
      }
    }
  };
  // dump wave's 2m x 2ch C-frags into both layouts (ch-half e)
  auto dumpCell = [&](ffrag (&v)[2][2], int colBase, int rowBase) {
#pragma unroll
    for (int i = 0; i < 2; ++i)
#pragma unroll
      for (int j = 0; j < 2; ++j) {
        const int chh = 32*e + 16*j + ln;
        const int n0 = 32*g + 16*i + 4*lq;
        unsigned short sv[4];
#pragma unroll
        for (int r = 0; r < 4; ++r) sv[r] = f2b(v[i][j][r]);
#pragma unroll
        for (int r = 0; r < 4; ++r) diffb[(n0 + r)*PD + colBase + chh] = sv[r];
        us4 q = {sv[0], sv[1], sv[2], sv[3]};
        *(us4*)&difT[(rowBase + chh)*PT + n0] = q;
      }
  };
  auto prebG16 = [&](bfrag (&bw)[16], const unsigned short* const (&bp)[4]) {
#pragma unroll
    for (int k = 0; k < 4; ++k)
#pragma unroll
      for (int n = 0; n < 4; ++n)
        bw[4*k+n] = *(const bfrag*)&bp[n][32*k + 8*lq];
  };
  auto prebC8 = [&](bfrag (&bw)[8], const unsigned short* const (&bp)[2]) {
#pragma unroll
    for (int k = 0; k < 4; ++k) {
      bw[2*k]   = *(const bfrag*)&bp[0][32*k + 8*lq];
      bw[2*k+1] = *(const bfrag*)&bp[1][32*k + 8*lq];
    }
  };
  auto waitge = [&](int* p, int seq) {
    if ((tid & 63) == 0) {
      int it = 0;
      while (__hip_atomic_load(p, __ATOMIC_RELAXED, __HIP_MEMORY_SCOPE_AGENT) < seq) {
        __builtin_amdgcn_s_sleep(4);
        if (++it > (1 << 22)) break;            // failsafe: never hard-hang
      }
    }
  };

  bfrag bw16[16];
  bfrag bw8[8];

  if (eta == 0) {
    // ===== Block A: L0. cols [x 0-15|x dm12 16-47|z 48-63|h dm0 64-127|h dm12 128-255|rh dm0 256-319]
    const unsigned short* bpg[4] = {
      wt + WT0G_OFF + (16*(2*e)     + ln)*256, wt + WT0G_OFF + (16*(2*e + 1) + ln)*256,
      wt + WT0G_OFF + (16*(4 + 2*e) + ln)*256, wt + WT0G_OFF + (16*(5 + 2*e) + ln)*256 };
    const unsigned short* bpc[2] = {
      wt + WT0C_OFF + (16*(2*e) + ln)*256, wt + WT0C_OFF + (16*(2*e + 1) + ln)*256 };
    const float bgr[2] = { b0g[32*e + ln], b0g[32*e + 16 + ln] };
    const float bgu[2] = { b0g[64 + 32*e + ln], b0g[64 + 32*e + 16 + ln] };
    const float bcv[2] = { b0c[32*e + ln], b0c[32*e + 16 + ln] };
    const int kofs0[8] = {0, 32, 128, 160, 192, 224, 256, 288};
    ffrag h0m[2][2] = {{fz, fz}, {fz, fz}};

    for (int i = tid; i < N_*16; i += 512)     // zero pad cols [48,64) once
      diffb[(i >> 4)*PD + 48 + (i & 15)] = 0;
    float4 xv = *(const float4*)&xseq[(size_t)(b*T_)*N_*DIN_ + 4*tid];

#pragma clang loop unroll(disable)
    for (int t = 0; t < L; ++t) {
      { // P1: stage x (cols 0-15 / difT rows 0-15); dump h0 (cols 64-127 / rows 16-79)
        const int node = tid >> 2, c = 4*(tid & 3);
        unsigned short s0 = f2b(xv.x), s1 = f2b(xv.y), s2 = f2b(xv.z), s3 = f2b(xv.w);
        us4 q = {s0, s1, s2, s3};
        *(us4*)&diffb[node*PD + c] = q;
        difT[(c+0)*PT + node] = s0; difT[(c+1)*PT + node] = s1;
        difT[(c+2)*PT + node] = s2; difT[(c+3)*PT + node] = s3;
        dumpCell(h0m, 64, 16);
        int tn = t + 1 < L ? t + 1 : L - 1;
        xv = *(const float4*)&xseq[(size_t)(b*T_ + tn)*N_*DIN_ + 4*tid];
        prebG16(bw16, bpg);
      }
      SYNC();                                            // BAR1
      if (e == 0) { diffuse(0, 16);  diffuse(1, 128); diffuse(2, 160); }
      else        { diffuse(3, 192); diffuse(4, 224); }
      SYNC();                                            // BAR2
      ffrag u0s[2][2], rh[2][2];
      {
        ffrag ga[2][4] = {{fz, fz, fz, fz}, {fz, fz, fz, fz}};
        gate4<8>(ga, bw16, arow0, arow1, bpg, lq);
#pragma unroll
        for (int i = 0; i < 2; ++i)
#pragma unroll
          for (int j = 0; j < 2; ++j)
#pragma unroll
            for (int r = 0; r < 4; ++r) {
              float rr = sigm(ga[i][j][r] + bgr[j]);
              rh[i][j][r]  = rr * h0m[i][j][r];
              u0s[i][j][r] = sigm(ga[i][2+j][r] + bgu[j]);
            }
      }
      // rh dm0 double-buffered -> cols 256-319 (no gate WAR); difT rows 16-79
      // were last read pre-BAR2 (diffuse1) -> safe to overwrite now.
      dumpCell(rh, 256, 16);
      prebC8(bw8, bpc);
      SYNC();                                            // BAR3
      if (e == 0) { diffuse(1, 128); diffuse(2, 160); }  // rh dm12 overwrite
      else        { diffuse(3, 192); diffuse(4, 224); }
      SYNC();                                            // BAR4
      {
        ffrag ca[2][2] = {{fz, fz}, {fz, fz}};
        cand2<8>(ca, bw8, arow0, arow1, kofs0, bpc, lq);
#pragma unroll
        for (int i = 0; i < 2; ++i)
#pragma unroll
          for (int j = 0; j < 2; ++j)
#pragma unroll
            for (int r = 0; r < 4; ++r) {
              float cc = tanh_(ca[i][j][r] + bcv[j]);
              float uu = u0s[i][j][r];
              h0m[i][j][r] = uu*h0m[i][j][r] + (1.f - uu)*cc;
            }
      }
      if (t >= 8) waitge(cons, t - 7);                   // FIFO backpressure
      { // send h0' ch-major [64 ch][128 nodes]
        unsigned short* slot = wt + FIFO_SLOT(b, t);
#pragma unroll
        for (int i = 0; i < 2; ++i)
#pragma unroll
          for (int j = 0; j < 2; ++j) {
            const int chh = 32*e + 16*j + ln;
            const int n0 = 32*g + 16*i + 4*lq;
            us4 q = {f2b(h0m[i][j][0]), f2b(h0m[i][j][1]),
                     f2b(h0m[i][j][2]), f2b(h0m[i][j][3])};
            *(us4*)&slot[chh*128 + n0] = q;
          }
      }
      __syncthreads();   // BAR5: drains sends (vmcnt) + protects LDS for next P1
      if (tid == 0)
        __hip_atomic_fetch_add(prod, 1, __ATOMIC_RELEASE, __HIP_MEMORY_SCOPE_AGENT);
    }
    return;
  }

  // ===== Block B: L1. cols [h0' dm0 0-63|h0' dm12 64-191|h1 dm0 192-255|h1/rh dm12 256-383|rh dm0 384-447]
  {
    const unsigned short* bpg[4] = {
      wt + WT1G_OFF + (16*(2*e)     + ln)*384, wt + WT1G_OFF + (16*(2*e + 1) + ln)*384,
      wt + WT1G_OFF + (16*(4 + 2*e) + ln)*384, wt + WT1G_OFF + (16*(5 + 2*e) + ln)*384 };
    const unsigned short* bpc[2] = {
      wt + WT1C_OFF + (16*(2*e) + ln)*384, wt + WT1C_OFF + (16*(2*e + 1) + ln)*384 };
    const float bgr[2] = { b1g[32*e + ln], b1g[32*e + 16 + ln] };
    const float bgu[2] = { b1g[64 + 32*e + ln], b1g[64 + 32*e + 16 + ln] };
    const float bcv[2] = { b1c[32*e + ln], b1c[32*e + 16 + ln] };
    const int kofs1[12] = {0, 32, 64, 96, 128, 160, 256, 288, 320, 352, 384, 416};
    ffrag h1m[2][2] = {{fz, fz}, {fz, fz}};
    ull pf[4];

    auto loadPf = [&](int tt) {
      const unsigned short* slot = wt + FIFO_SLOT(b, tt);
#pragma unroll
      for (int rep = 0; rep < 4; ++rep) {
        const int idx = tid + 512*rep;
        const int ch = idx >> 5, n0 = (idx & 31)*4;
        pf[rep] = __hip_atomic_load((const ull*)&slot[ch*128 + n0],
                                    __ATOMIC_RELAXED, __HIP_MEMORY_SCOPE_AGENT);
      }
    };

    waitge(prod, 1);
    loadPf(0);

#pragma clang loop unroll(disable)
    for (int t = 0; t < L; ++t) {
      { // P1: scatter h0'(t) from regs; dump h1 (cols 192-255 / difT rows 64-127)
#pragma unroll
        for (int rep = 0; rep < 4; ++rep) {
          const int idx = tid + 512*rep;
          const int ch = idx >> 5, n0 = (idx & 31)*4;
          *(ull*)&difT[ch*PT + n0] = pf[rep];
          union { ull u; unsigned short s[4]; } cv; cv.u = pf[rep];
#pragma unroll
          for (int j = 0; j < 4; ++j) diffb[(n0 + j)*PD + ch] = cv.s[j];
        }
        dumpCell(h1m, 192, 64);
        prebG16(bw16, bpg);
      }
      SYNC();                                            // BAR1
      if (tid == 0)
        __hip_atomic_fetch_add(cons, 1, __ATOMIC_RELEASE, __HIP_MEMORY_SCOPE_AGENT);
      if (e == 0) { diffuse(0, 64);  diffuse(1, 96);  diffuse(2, 128); diffuse(3, 160); }
      else        { diffuse(4, 256); diffuse(5, 288); diffuse(6, 320); diffuse(7, 352); }
      { // prefetch next FIFO slot into regs (A runs ahead; off critical path)
        int sq = t + 2 < L ? t + 2 : L;
        waitge(prod, sq);
        loadPf(t + 1 < L ? t + 1 : L - 1);
      }
      SYNC();                                            // BAR2
      ffrag u1s[2][2], rh[2][2];
      {
        ffrag ga[2][4] = {{fz, fz, fz, fz}, {fz, fz, fz, fz}};
        gate4<12>(ga, bw16, arow0, arow1, bpg, lq);
#pragma unroll
        for (int i = 0; i < 2; ++i)
#pragma unroll
          for (int j = 0; j < 2; ++j)
#pragma unroll
            for (int r = 0; r < 4; ++r) {
              float rr = sigm(ga[i][j][r] + bgr[j]);
              rh[i][j][r]  = rr * h1m[i][j][r];
              u1s[i][j][r] = sigm(ga[i][2+j][r] + bgu[j]);
            }
      }
      dumpCell(rh, 384, 64);     // rh dm0 -> fresh cols; difT rows 64-127 safe post-BAR2
      prebC8(bw8, bpc);
      SYNC();                                            // BAR3
      if (e == 0) { diffuse(4, 256); diffuse(5, 288); }  // rh dm12 overwrite
      else        { diffuse(6, 320); diffuse(7, 352); }
      SYNC();                                            // BAR4
      {
        ffrag ca[2][2] = {{fz, fz}, {fz, fz}};
        cand2<12>(ca, bw8, arow0, arow1, kofs1, bpc, lq);
#pragma unroll
        for (int i = 0; i < 2; ++i)
#pragma unroll
          for (int j = 0; j < 2; ++j)
#pragma unroll
            for (int r = 0; r < 4; ++r) {
              float cc = tanh_(ca[i][j][r] + bcv[j]);
              float uu = u1s[i][j][r];
              h1m[i][j][r] = uu*h1m[i][j][r] + (1.f - uu)*cc;
            }
      }
      SYNC();                                            // BAR5 (cand reads done)
    }

    // Head: relu(h1) @ W_fc + b_fc, max over nodes
    {
      float* hb = (float*)lds;                  // [128][64]
#pragma unroll
      for (int i = 0; i < 2; ++i)
#pragma unroll
        for (int j = 0; j < 2; ++j)
#pragma unroll
          for (int r = 0; r < 4; ++r) {
            float v = h1m[i][j][r];
            hb[(32*g + 16*i + 4*lq + r)*U_ + 32*e + 16*j + ln] = v > 0.f ? v : 0.f;
          }
    }
    __syncthreads();
    float* hb = (float*)lds;
    float* lb = hb + N_*U_;
    if (tid < N_) {
      float lg[4];
#pragma unroll
      for (int j = 0; j < 4; ++j) lg[j] = bfc[j];
      for (int ch = 0; ch < U_; ++ch) {
        float v = hb[tid*U_ + ch];
#pragma unroll
        for (int j = 0; j < 4; ++j) lg[j] += v * wfc[ch*4 + j];
      }
#pragma unroll
      for (int j = 0; j < 4; ++j) lb[tid*4 + j] = lg[j];
    }
    __syncthreads();
    if (tid < 4) {
      float m = lb[tid];
      for (int n = 1; n < N_; ++n) m = fmaxf(m, lb[n*4 + tid]);
      out[b*4 + tid] = m;
    }
  }
}

extern "C" void kernel_launch(void* const* d_in, const int* in_sizes, int n_in,
                              void* d_out, int out_size, void* d_ws, size_t ws_size,
                              hipStream_t stream) {
  const float* xseq = (const float*)d_in[0];
  const int*   slen = (const int*)  d_in[1];
  const float* sup  = (const float*)d_in[2];
  const float* w0g  = (const float*)d_in[3];
  const float* b0g  = (const float*)d_in[4];
  const float* w0c  = (const float*)d_in[5];
  const float* b0c  = (const float*)d_in[6];
  const float* w1g  = (const float*)d_in[7];
  const float* b1g  = (const float*)d_in[8];
  const float* w1c  = (const float*)d_in[9];
  const float* b1c  = (const float*)d_in[10];
  const float* wfc  = (const float*)d_in[11];
  const float* bfc  = (const float*)d_in[12];
  float* out = (float*)d_out;
  unsigned short* wt = (unsigned short*)d_ws;

  (void)hipFuncSetAttribute((const void*)dcgru,
                            hipFuncAttributeMaxDynamicSharedMemorySize, LDS_BYTES);
  zero_flags<<<dim3(1), dim3(64), 0, stream>>>(wt);
  setup_wt<<<dim3((WT_TOTAL + 255)/256), dim3(256), 0, stream>>>(w0g, w0c, w1g, w1c, wt);
  setup_s2<<<dim3(64), dim3(256), 0, stream>>>(sup, wt + S2_OFF);
  dcgru<<<dim3(64), dim3(512), LDS_BYTES, stream>>>(
      xseq, slen, sup, b0g, b0c, b1g, b1c, wfc, bfc, wt, out);
}